// Round 7
// baseline (192.479 us; speedup 1.0000x reference)
//
#include <hip/hip_runtime.h>
#include <math.h>

// Problem constants
#define D_DOM 64
#define S_RES 512
#define R_ROWS 2048
#define NAA 20
#define NF 12
#define NB 2
#define NJ 24       // NB*NF
#define NPC 8       // p-chunks per domain: 256 adjs rows = 128 p each
#define PROWS 16    // p per batch (= 32 adjs rows, 64 KB f32)
#define BR 32       // adjs rows per batch
#define NBATCH 8    // batches per chunk
#define BSTR 1032   // padded bf16 row stride of Bs (+8 bf16 = 16B pad)

typedef unsigned short ushort_t;
typedef unsigned int uint_t;
typedef short bf16x8 __attribute__((ext_vector_type(8)));   // 8 bf16 = 4 VGPR
typedef float f32x4 __attribute__((ext_vector_type(4)));

// bf16 helpers (RNE), dependency-free
__device__ __forceinline__ ushort_t f2bf(float x) {
  uint_t u = __float_as_uint(x);
  uint_t r = u + 0x7FFFu + ((u >> 16) & 1u);
  return (ushort_t)(r >> 16);
}
__device__ __forceinline__ float bflo(uint_t u) { return __uint_as_float(u << 16); }
__device__ __forceinline__ float bfhi(uint_t u) { return __uint_as_float(u & 0xFFFF0000u); }

// ---------------------------------------------------------------------------
// Kernel A: G[d][j][k] bf16, k in [0,1024): k<512 -> g0[j,s]=sum_c aa*w[f,c,0],
// k>=512 -> g1[j,s] (s = k-512). j = b*12+f.
// ---------------------------------------------------------------------------
__global__ __launch_bounds__(256) void kA_g(const float* __restrict__ aa,
                                            const float* __restrict__ wconv,
                                            ushort_t* __restrict__ g) {
  __shared__ float ws[NF * NAA * 2];
  const int tid = threadIdx.x;
  for (int i = tid; i < NF * NAA * 2; i += 256) ws[i] = wconv[i];
  __syncthreads();
  const int pos = blockIdx.x * 256 + tid;  // d*512 + s
  float av[NB][NAA];
#pragma unroll
  for (int b = 0; b < NB; ++b)
#pragma unroll
    for (int c = 0; c < NAA; ++c)
      av[b][c] = aa[(size_t)(b * NAA + c) * (D_DOM * S_RES) + pos];
  const int d = pos >> 9;
  const int s = pos & 511;
#pragma unroll
  for (int b = 0; b < NB; ++b)
#pragma unroll
    for (int f = 0; f < NF; ++f) {
      float s0 = 0.f, s1 = 0.f;
#pragma unroll
      for (int c = 0; c < NAA; ++c) {
        const float a = av[b][c];
        s0 = fmaf(a, ws[(f * NAA + c) * 2 + 0], s0);
        s1 = fmaf(a, ws[(f * NAA + c) * 2 + 1], s1);
      }
      const int j = b * NF + f;
      g[((size_t)(d * NJ + j)) * 1024 + s] = f2bf(s0);
      g[((size_t)(d * NJ + j)) * 1024 + 512 + s] = f2bf(s1);
    }
}

// ---------------------------------------------------------------------------
// Kernel B: per block (d, pc): 256 adjs rows = 128 p, 8 batches of 16 p.
// Per batch: reg-stage adjs f32 -> bf16 LDS Bs[16][1032]; h-GEMM on MFMA
// (h[j,p] = sum_k G[j,k]*B[k,p], K=1024 as even|odd concat); y-GEMM on VALU
// f32 (y[j,s] += h[j,p]*Ae[p,s]); deg summed from Bs.
// Waves: w=(mt,kh): mt=j-tile (0:j0-15, 1:j16-31 pad>=24), kh=K half.
// 16x16x32 bf16 lane layout: A: lane l -> row l&15, k=(l>>4)*8+i;
// B: col l&15, k=(l>>4)*8+i; D: col l&15, row=(l>>4)*4+i  [m89].
// NO min-waves launch_bounds (round-5 spill disaster).
// ---------------------------------------------------------------------------
__global__ __launch_bounds__(256) void kB_main(const float* __restrict__ adjs,
                                               const ushort_t* __restrict__ g,
                                               float* __restrict__ yp,
                                               float* __restrict__ degp) {
  const int tid = threadIdx.x;
  const int w = tid >> 6;   // 0..3
  const int l = tid & 63;
  const int d = blockIdx.x >> 3;
  const int pc = blockIdx.x & 7;

  __shared__ __align__(16) ushort_t Bs[2][PROWS][BSTR];  // 66 KB, bf16, dbuf
  __shared__ __align__(16) float hs[2][2][16][16];       // [kh][mt][j][p] 4 KB

  const int mt = w & 1, kh = w >> 1;
  const int jl = l & 15, kg = l >> 4;

  const float* ablk = adjs + ((size_t)d * R_ROWS + (size_t)pc * 256) * S_RES;

  // G fragments in registers: this wave's (mt, kh): 16 ksteps x 8 bf16.
  bf16x8 gf[16];
  {
    const int j = mt * 16 + jl;
    const bool valid = (j < NJ);
    const ushort_t* gr =
        g + ((size_t)(d * NJ + (valid ? j : 0))) * 1024 + kh * 512 + kg * 8;
    const bf16x8 z = {};
#pragma unroll
    for (int ks = 0; ks < 16; ++ks) {
      bf16x8 v = *(const bf16x8*)(gr + ks * 32);
      gf[ks] = valid ? v : z;
    }
  }

  float yv[6][8];  // y acc: wave's 6 j x lane's 8 s (s = l*8..l*8+7)
#pragma unroll
  for (int jj = 0; jj < 6; ++jj)
#pragma unroll
    for (int e = 0; e < 8; ++e) yv[jj][e] = 0.f;
  float dg0 = 0.f, dg1 = 0.f;  // deg partial: s = w*128 + 2l (+1)

  float4 tmp[16];  // staged f32 adjs: unit u=tid+256m -> row u>>7, colu u&127

#define LOADR(T)                                                               \
  {                                                                            \
    _Pragma("unroll") for (int m = 0; m < 16; ++m) {                           \
      const int u = tid + 256 * m;                                             \
      tmp[m] = *(const float4*)(ablk + ((size_t)((T)*BR + (u >> 7))) * S_RES + \
                                (u & 127) * 4);                                \
    }                                                                          \
  }
#define CVTW(BUF)                                                              \
  {                                                                            \
    _Pragma("unroll") for (int m = 0; m < 16; ++m) {                           \
      const int u = tid + 256 * m;                                             \
      const int r_ = u >> 7, cu_ = u & 127;                                    \
      ushort4 h4;                                                              \
      h4.x = f2bf(tmp[m].x); h4.y = f2bf(tmp[m].y);                            \
      h4.z = f2bf(tmp[m].z); h4.w = f2bf(tmp[m].w);                            \
      *(ushort4*)&Bs[(BUF)][r_ >> 1][(r_ & 1) * 512 + cu_ * 4] = h4;           \
    }                                                                          \
  }

  LOADR(0);
  CVTW(0);
  __syncthreads();

  for (int t = 0; t < NBATCH; ++t) {
    const int cur = t & 1;
    if (t + 1 < NBATCH) LOADR(t + 1);  // loads stay in flight until CVTW

    // ---- deg from Bs[cur]: wave w owns s in [w*128, w*128+128), lane 2 s.
#pragma unroll
    for (int p = 0; p < PROWS; ++p) {
      const uint_t e = *(const uint_t*)&Bs[cur][p][w * 128 + 2 * l];
      const uint_t o = *(const uint_t*)&Bs[cur][p][512 + w * 128 + 2 * l];
      dg0 += bflo(e) + bflo(o);
      dg1 += bfhi(e) + bfhi(o);
    }

    // ---- h-GEMM: 16 MFMA, K = kh*512..+512, output tile (mt) x 16 p.
    {
      f32x4 acc = {0.f, 0.f, 0.f, 0.f};
#pragma unroll
      for (int ks = 0; ks < 16; ++ks) {
        const bf16x8 bfr =
            *(const bf16x8*)&Bs[cur][jl][kh * 512 + ks * 32 + kg * 8];
        acc = __builtin_amdgcn_mfma_f32_16x16x32_bf16(gf[ks], bfr, acc, 0, 0, 0);
      }
#pragma unroll
      for (int i = 0; i < 4; ++i) hs[kh][mt][kg * 4 + i][jl] = acc[i];
    }
    __syncthreads();  // hs ready

    // ---- y-phase: y[j, s] += sum_p h[j,p] * Ae[p,s]; Ae from Bs[cur] k<512.
#pragma unroll
    for (int pg = 0; pg < 4; ++pg) {
      float ae[4][8];
#pragma unroll
      for (int q = 0; q < 4; ++q) {
        const uint4 v = *(const uint4*)&Bs[cur][pg * 4 + q][l * 8];
        ae[q][0] = bflo(v.x); ae[q][1] = bfhi(v.x);
        ae[q][2] = bflo(v.y); ae[q][3] = bfhi(v.y);
        ae[q][4] = bflo(v.z); ae[q][5] = bfhi(v.z);
        ae[q][6] = bflo(v.w); ae[q][7] = bfhi(v.w);
      }
#pragma unroll
      for (int jj = 0; jj < 6; ++jj) {
        const int j = w * 6 + jj;
        const int jt = j >> 4, jlo = j & 15;
        const f32x4 ha = *(const f32x4*)&hs[0][jt][jlo][pg * 4];
        const f32x4 hb = *(const f32x4*)&hs[1][jt][jlo][pg * 4];
        const f32x4 hsum = ha + hb;
#pragma unroll
        for (int q = 0; q < 4; ++q) {
          const float hv = hsum[q];
#pragma unroll
          for (int e = 0; e < 8; ++e) yv[jj][e] = fmaf(hv, ae[q][e], yv[jj][e]);
        }
      }
    }

    if (t + 1 < NBATCH) CVTW(cur ^ 1);  // write next batch (disjoint buffer)
    __syncthreads();  // Bs[nxt] ready; hs reads done before next overwrite
  }

  // ---- epilogue: y partials f32, deg partials f32
#pragma unroll
  for (int jj = 0; jj < 6; ++jj) {
    const int j = w * 6 + jj;
    float* yrow = yp + ((size_t)((pc * D_DOM + d) * NJ + j)) * S_RES + l * 8;
    *(float4*)yrow = make_float4(yv[jj][0], yv[jj][1], yv[jj][2], yv[jj][3]);
    *(float4*)(yrow + 4) = make_float4(yv[jj][4], yv[jj][5], yv[jj][6], yv[jj][7]);
  }
  *(float2*)&degp[((size_t)d * NPC + pc) * S_RES + w * 128 + 2 * l] =
      make_float2(dg0, dg1);
}

// ---------------------------------------------------------------------------
// Kernel D: reduce yp/degp over pc, max-pool over s, combine, sigmoid.
// One block per domain; lane owns s-pair {2t, 2t+1}.
// ---------------------------------------------------------------------------
__global__ __launch_bounds__(256) void kD_final(const float* __restrict__ yp,
                                                const float* __restrict__ degp,
                                                const float* __restrict__ wcomb,
                                                float* __restrict__ out) {
  const int d = blockIdx.x;
  const int tid = threadIdx.x;
  const int tj = tid >> 6;
  __shared__ float wm[NJ][4];
  __shared__ float pool[NJ];

  float dg0 = 0.f, dg1 = 0.f;
#pragma unroll
  for (int pc = 0; pc < NPC; ++pc) {
    const float2 dv = *(const float2*)(degp + ((size_t)d * NPC + pc) * S_RES + 2 * tid);
    dg0 += dv.x;
    dg1 += dv.y;
  }
  const float q0 = 1.0f / dg0;
  const float q1 = 1.0f / dg1;

  for (int j = 0; j < NJ; ++j) {
    float v0 = 0.f, v1 = 0.f;
#pragma unroll
    for (int pc = 0; pc < NPC; ++pc) {
      const float2 yv =
          *(const float2*)(yp + ((size_t)((pc * D_DOM + d) * NJ + j)) * S_RES + 2 * tid);
      v0 += yv.x;
      v1 += yv.y;
    }
    float m = fmaxf(v0 * q0, v1 * q1);
#pragma unroll
    for (int mask = 32; mask; mask >>= 1) m = fmaxf(m, __shfl_xor(m, mask));
    if ((tid & 63) == 0) wm[j][tj] = m;
  }
  __syncthreads();
  if (tid < NJ) {
    float m = wm[tid][0];
    m = fmaxf(m, wm[tid][1]);
    m = fmaxf(m, wm[tid][2]);
    m = fmaxf(m, wm[tid][3]);
    pool[tid] = m;
  }
  __syncthreads();
  if (tid < NB) {
    float sc = 0.f;
#pragma unroll
    for (int f = 0; f < NF; ++f) sc = fmaf(pool[tid * NF + f], wcomb[f], sc);
    out[d * NB + tid] = 1.0f / (1.0f + expf(-sc));
  }
}

// ---------------------------------------------------------------------------
extern "C" void kernel_launch(void* const* d_in, const int* in_sizes, int n_in,
                              void* d_out, int out_size, void* d_ws, size_t ws_size,
                              hipStream_t stream) {
  const float* aa = (const float*)d_in[0];
  const float* adjs = (const float*)d_in[1];
  const float* wconv = (const float*)d_in[2];
  const float* wcomb = (const float*)d_in[3];
  float* out = (float*)d_out;
  char* wsb = (char*)d_ws;

  // ws layout (bytes):
  //   g    bf16 [64][24][1024] = 3,145,728
  //   yp   f32  [8][64][24][512] = 25,165,824
  //   degp f32  [64][8][512] = 1,048,576     (total 29,360,128)
  ushort_t* g = (ushort_t*)wsb;
  float* yp = (float*)(wsb + 3145728);
  float* degp = (float*)(wsb + 3145728 + 25165824);

  kA_g<<<dim3(128), dim3(256), 0, stream>>>(aa, wconv, g);
  kB_main<<<dim3(512), dim3(256), 0, stream>>>(adjs, g, yp, degp);
  kD_final<<<dim3(64), dim3(256), 0, stream>>>(yp, degp, wcomb, out);
}

// Round 8
// 134.849 us; speedup vs baseline: 1.4274x; 1.4274x over previous
//
#include <hip/hip_runtime.h>
#include <math.h>

// Problem constants
#define D_DOM 64
#define S_RES 512
#define R_ROWS 2048
#define NAA 20
#define NF 12
#define NB 2
#define NJ 24       // NB*NF
#define NPC 16      // p-chunks per domain (128 rows each)
#define BROWS 8     // rows per stage batch (16 KB f32)
#define NBATCH 16   // batches per block
#define NBUF 3      // pipeline depth (2 batches in flight)

typedef unsigned short ushort_t;
typedef unsigned int uint_t;

// bf16 helpers (RNE), dependency-free
__device__ __forceinline__ ushort_t f2bf(float x) {
  uint_t u = __float_as_uint(x);
  uint_t r = u + 0x7FFFu + ((u >> 16) & 1u);
  return (ushort_t)(r >> 16);
}
__device__ __forceinline__ float bf2f(ushort_t h) {
  return __uint_as_float(((uint_t)h) << 16);
}

// Direct global->LDS DMA, 16 B/lane. LDS dest wave-uniform base.
__device__ __forceinline__ void gload_lds16(const float* g, float* l) {
  __builtin_amdgcn_global_load_lds((const __attribute__((address_space(1))) void*)g,
                                   (__attribute__((address_space(3))) void*)l,
                                   16, 0, 0);
}

// ---------------------------------------------------------------------------
// Kernel A: g[d][k][j][s] bf16 = sum_c aa[b,c,d*512+s] * w_conv[f,c,k]
// ---------------------------------------------------------------------------
__global__ __launch_bounds__(256) void kA_g(const float* __restrict__ aa,
                                            const float* __restrict__ wconv,
                                            ushort_t* __restrict__ g) {
  __shared__ float ws[NF * NAA * 2];
  const int tid = threadIdx.x;
  for (int i = tid; i < NF * NAA * 2; i += 256) ws[i] = wconv[i];
  __syncthreads();
  const int pos = blockIdx.x * 256 + tid;  // d*512 + s
  float av[NB][NAA];
#pragma unroll
  for (int b = 0; b < NB; ++b)
#pragma unroll
    for (int c = 0; c < NAA; ++c)
      av[b][c] = aa[(size_t)(b * NAA + c) * (D_DOM * S_RES) + pos];
  const int d = pos >> 9;
  const int s = pos & 511;
#pragma unroll
  for (int b = 0; b < NB; ++b)
#pragma unroll
    for (int f = 0; f < NF; ++f) {
      float s0 = 0.f, s1 = 0.f;
#pragma unroll
      for (int c = 0; c < NAA; ++c) {
        const float a = av[b][c];
        s0 = fmaf(a, ws[(f * NAA + c) * 2 + 0], s0);
        s1 = fmaf(a, ws[(f * NAA + c) * 2 + 1], s1);
      }
      const int j = b * NF + f;
      g[((size_t)(d * 2 + 0) * NJ + j) * S_RES + s] = f2bf(s0);
      g[((size_t)(d * 2 + 1) * NJ + j) * S_RES + s] = f2bf(s1);
    }
}

// ---------------------------------------------------------------------------
// DPP 64-lane sum (VALU pipe). Result broadcast via readlane(63).
// ---------------------------------------------------------------------------
__device__ __forceinline__ float wave_sum64(float x) {
  int v;
  v = __builtin_amdgcn_update_dpp(0, __float_as_int(x), 0x111, 0xf, 0xf, true); // row_shr:1
  x += __int_as_float(v);
  v = __builtin_amdgcn_update_dpp(0, __float_as_int(x), 0x112, 0xf, 0xf, true); // row_shr:2
  x += __int_as_float(v);
  v = __builtin_amdgcn_update_dpp(0, __float_as_int(x), 0x114, 0xf, 0xf, true); // row_shr:4
  x += __int_as_float(v);
  v = __builtin_amdgcn_update_dpp(0, __float_as_int(x), 0x118, 0xf, 0xf, true); // row_shr:8
  x += __int_as_float(v);
  v = __builtin_amdgcn_update_dpp(0, __float_as_int(x), 0x142, 0xf, 0xf, true); // row_bcast15
  x += __int_as_float(v);
  v = __builtin_amdgcn_update_dpp(0, __float_as_int(x), 0x143, 0xf, 0xf, true); // row_bcast31
  x += __int_as_float(v);
  return __int_as_float(__builtin_amdgcn_readlane(__float_as_int(x), 63));
}

// ---------------------------------------------------------------------------
// Kernel B: fused single pass over adjs. R4 compute core + 3-deep
// gload_lds pipeline with COUNTED vmcnt (never 0 in loop) + raw s_barrier.
// Rationale: __syncthreads emits s_waitcnt vmcnt(0), draining the
// just-issued prefetch every batch (R6's flaw). Counted vmcnt(4) waits
// only for the batch about to be computed; the next 1-2 batches stay in
// flight across the barrier.
// Safety: a wave past barrier_t implies ALL waves finished compute(t-1)
// (s_barrier releases only when all arrive), so STAGE(t+2) overwriting
// buf[(t-1)%3] after the barrier is race-free.
// 1024 blocks x 256 thr (4 waves); block=(d,pc) covers 128 rows.
// wave tj owns j = tj*6+jj ; lane tp owns s in {4tp..} U {256+4tp..}
// NO min-waves launch_bounds (round-5 spill disaster).
// ---------------------------------------------------------------------------
__global__ __launch_bounds__(256) void kB_main(const float* __restrict__ adjs,
                                               const ushort_t* __restrict__ g,
                                               ushort_t* __restrict__ yp,
                                               float* __restrict__ degp) {
  const int tid = threadIdx.x;
  const int tj = tid >> 6;   // 0..3
  const int tp = tid & 63;
  const int bid = blockIdx.x;
  const int d = bid >> 4;
  const int pc = bid & 15;

  __shared__ float rows[NBUF][BROWS][S_RES];  // 3 x 16 KB

  const float* ablk = adjs + ((size_t)d * R_ROWS + (size_t)pc * 128) * S_RES;

  // Preload this wave's 6 g fragments (bf16 -> f32 registers, one-time).
  float4 g0A[6], g0B[6], g1A[6], g1B[6];
  const ushort_t* gd = g + (size_t)d * 2 * NJ * S_RES;
#pragma unroll
  for (int jj = 0; jj < 6; ++jj) {
    const int j = tj * 6 + jj;
    ushort4 u;
    u = *(const ushort4*)(gd + (size_t)(0 * NJ + j) * S_RES + 4 * tp);
    g0A[jj] = make_float4(bf2f(u.x), bf2f(u.y), bf2f(u.z), bf2f(u.w));
    u = *(const ushort4*)(gd + (size_t)(0 * NJ + j) * S_RES + 256 + 4 * tp);
    g0B[jj] = make_float4(bf2f(u.x), bf2f(u.y), bf2f(u.z), bf2f(u.w));
    u = *(const ushort4*)(gd + (size_t)(1 * NJ + j) * S_RES + 4 * tp);
    g1A[jj] = make_float4(bf2f(u.x), bf2f(u.y), bf2f(u.z), bf2f(u.w));
    u = *(const ushort4*)(gd + (size_t)(1 * NJ + j) * S_RES + 256 + 4 * tp);
    g1B[jj] = make_float4(bf2f(u.x), bf2f(u.y), bf2f(u.z), bf2f(u.w));
  }

  float4 accA[6], accB[6];
#pragma unroll
  for (int jj = 0; jj < 6; ++jj) {
    accA[jj] = make_float4(0.f, 0.f, 0.f, 0.f);
    accB[jj] = make_float4(0.f, 0.f, 0.f, 0.f);
  }
  float4 degA = make_float4(0.f, 0.f, 0.f, 0.f);
  float4 degB = make_float4(0.f, 0.f, 0.f, 0.f);

  // stage batch (8 rows = 16 KB): 16 wave-units; wave tj issues 4.
#define STAGE(BATCH, BUF)                                                      \
  {                                                                            \
    _Pragma("unroll")                                                          \
    for (int q = 0; q < 4; ++q) {                                              \
      const int u_ = tj * 4 + q;                                               \
      const int row_ = u_ >> 1;                                                \
      const int half_ = u_ & 1;                                                \
      gload_lds16(ablk + ((size_t)((BATCH)*BROWS + row_)) * S_RES +            \
                      half_ * 256 + tp * 4,                                    \
                  &rows[(BUF)][row_][half_ * 256]);                            \
    }                                                                          \
  }

  STAGE(0, 0);
  STAGE(1, 1);
  int cur = 0, sb = 2;

  for (int t = 0; t < NBATCH; ++t) {
    // wait ONLY for batch t (allow batch t+1's 4 loads to stay in flight)
    if (t < NBATCH - 1) {
      asm volatile("s_waitcnt vmcnt(4)" ::: "memory");
    } else {
      asm volatile("s_waitcnt vmcnt(0)" ::: "memory");
    }
    __builtin_amdgcn_s_barrier();
    asm volatile("" ::: "memory");
    if (t + 2 < NBATCH) STAGE(t + 2, sb);

#pragma unroll
    for (int pb = 0; pb < BROWS / 2; ++pb) {
      const float4 reA = *(const float4*)&rows[cur][2 * pb][4 * tp];
      const float4 reB = *(const float4*)&rows[cur][2 * pb][256 + 4 * tp];
      const float4 roA = *(const float4*)&rows[cur][2 * pb + 1][4 * tp];
      const float4 roB = *(const float4*)&rows[cur][2 * pb + 1][256 + 4 * tp];

      if (tj == 0) {  // wave-uniform branch
        degA.x += reA.x + roA.x; degA.y += reA.y + roA.y;
        degA.z += reA.z + roA.z; degA.w += reA.w + roA.w;
        degB.x += reB.x + roB.x; degB.y += reB.y + roB.y;
        degB.z += reB.z + roB.z; degB.w += reB.w + roB.w;
      }

#pragma unroll
      for (int jj = 0; jj < 6; ++jj) {
        float p = reA.x * g0A[jj].x;
        p = fmaf(reA.y, g0A[jj].y, p);
        p = fmaf(reA.z, g0A[jj].z, p);
        p = fmaf(reA.w, g0A[jj].w, p);
        p = fmaf(reB.x, g0B[jj].x, p);
        p = fmaf(reB.y, g0B[jj].y, p);
        p = fmaf(reB.z, g0B[jj].z, p);
        p = fmaf(reB.w, g0B[jj].w, p);
        p = fmaf(roA.x, g1A[jj].x, p);
        p = fmaf(roA.y, g1A[jj].y, p);
        p = fmaf(roA.z, g1A[jj].z, p);
        p = fmaf(roA.w, g1A[jj].w, p);
        p = fmaf(roB.x, g1B[jj].x, p);
        p = fmaf(roB.y, g1B[jj].y, p);
        p = fmaf(roB.z, g1B[jj].z, p);
        p = fmaf(roB.w, g1B[jj].w, p);
        const float h = wave_sum64(p);  // h[j, p] complete, uniform
        accA[jj].x = fmaf(h, reA.x, accA[jj].x);
        accA[jj].y = fmaf(h, reA.y, accA[jj].y);
        accA[jj].z = fmaf(h, reA.z, accA[jj].z);
        accA[jj].w = fmaf(h, reA.w, accA[jj].w);
        accB[jj].x = fmaf(h, reB.x, accB[jj].x);
        accB[jj].y = fmaf(h, reB.y, accB[jj].y);
        accB[jj].z = fmaf(h, reB.z, accB[jj].z);
        accB[jj].w = fmaf(h, reB.w, accB[jj].w);
      }
    }
    cur = (cur == NBUF - 1) ? 0 : cur + 1;
    sb = (sb == NBUF - 1) ? 0 : sb + 1;
  }

  // write y partials (bf16, per pc) and deg partials (f32)
  ushort_t* ypb = yp + (size_t)(pc * D_DOM + d) * NJ * S_RES;
#pragma unroll
  for (int jj = 0; jj < 6; ++jj) {
    const int j = tj * 6 + jj;
    ushort4 ua, ub;
    ua.x = f2bf(accA[jj].x); ua.y = f2bf(accA[jj].y);
    ua.z = f2bf(accA[jj].z); ua.w = f2bf(accA[jj].w);
    ub.x = f2bf(accB[jj].x); ub.y = f2bf(accB[jj].y);
    ub.z = f2bf(accB[jj].z); ub.w = f2bf(accB[jj].w);
    *(ushort4*)(ypb + (size_t)j * S_RES + 4 * tp) = ua;
    *(ushort4*)(ypb + (size_t)j * S_RES + 256 + 4 * tp) = ub;
  }
  if (tj == 0) {
    float* dp = degp + ((size_t)d * NPC + pc) * S_RES;
    *(float4*)(dp + 4 * tp) = degA;
    *(float4*)(dp + 256 + 4 * tp) = degB;
  }
}

// ---------------------------------------------------------------------------
// Kernel D0: rdeg[d][s] = 1 / sum_pc degp. 64 blocks x 256 thr (2 s each).
// ---------------------------------------------------------------------------
__global__ __launch_bounds__(256) void kD0_rdeg(const float* __restrict__ degp,
                                                float* __restrict__ rdeg) {
  const int d = blockIdx.x;
  const int tid = threadIdx.x;
  float dg0 = 0.f, dg1 = 0.f;
#pragma unroll
  for (int pc = 0; pc < NPC; ++pc) {
    const float2 dv = *(const float2*)(degp + ((size_t)d * NPC + pc) * S_RES + 2 * tid);
    dg0 += dv.x;
    dg1 += dv.y;
  }
  *(float2*)(rdeg + (size_t)d * S_RES + 2 * tid) = make_float2(1.f / dg0, 1.f / dg1);
}

// ---------------------------------------------------------------------------
// Kernel D1: pooled[d][j] = max_s (sum_pc yp) * rdeg.  grid (24, 64).
// ---------------------------------------------------------------------------
__global__ __launch_bounds__(256) void kD1_pool(const ushort_t* __restrict__ yp,
                                                const float* __restrict__ rdeg,
                                                float* __restrict__ pool) {
  const int j = blockIdx.x;
  const int d = blockIdx.y;
  const int tid = threadIdx.x;
  __shared__ float wmax[4];

  float v0 = 0.f, v1 = 0.f;
#pragma unroll
  for (int pc = 0; pc < NPC; ++pc) {
    const ushort2 yv =
        *(const ushort2*)(yp + ((size_t)(pc * D_DOM + d) * NJ + j) * S_RES + 2 * tid);
    v0 += bf2f(yv.x);
    v1 += bf2f(yv.y);
  }
  const float2 rv = *(const float2*)(rdeg + (size_t)d * S_RES + 2 * tid);
  float m = fmaxf(v0 * rv.x, v1 * rv.y);
#pragma unroll
  for (int mask = 32; mask; mask >>= 1) m = fmaxf(m, __shfl_xor(m, mask));
  if ((tid & 63) == 0) wmax[tid >> 6] = m;
  __syncthreads();
  if (tid == 0)
    pool[d * NJ + j] =
        fmaxf(fmaxf(wmax[0], wmax[1]), fmaxf(wmax[2], wmax[3]));
}

// ---------------------------------------------------------------------------
// Kernel D2: out[d*B+b] = sigmoid(sum_f pooled[d][b*12+f] * w[f]). 1 block.
// ---------------------------------------------------------------------------
__global__ __launch_bounds__(128) void kD2_out(const float* __restrict__ pool,
                                               const float* __restrict__ wcomb,
                                               float* __restrict__ out) {
  const int t = threadIdx.x;
  if (t < D_DOM * NB) {
    const int d = t >> 1, b = t & 1;
    float sc = 0.f;
#pragma unroll
    for (int f = 0; f < NF; ++f) sc = fmaf(pool[d * NJ + b * NF + f], wcomb[f], sc);
    out[t] = 1.0f / (1.0f + expf(-sc));
  }
}

// ---------------------------------------------------------------------------
extern "C" void kernel_launch(void* const* d_in, const int* in_sizes, int n_in,
                              void* d_out, int out_size, void* d_ws, size_t ws_size,
                              hipStream_t stream) {
  const float* aa = (const float*)d_in[0];
  const float* adjs = (const float*)d_in[1];
  const float* wconv = (const float*)d_in[2];
  const float* wcomb = (const float*)d_in[3];
  float* out = (float*)d_out;
  char* wsb = (char*)d_ws;

  // ws layout (bytes):
  //   g    bf16 [64*2*24*512]  @ 0          = 3,145,728
  //   yp   bf16 [16*64*24*512] @ 3,145,728  = 25,165,824
  //   degp f32  [64*16*512]    @ 28,311,552 = 2,097,152
  //   rdeg f32  [64*512]       @ 30,408,704 = 131,072
  //   pool f32  [64*24]        @ 30,539,776 = 6,144      (total 30,545,920)
  ushort_t* g = (ushort_t*)wsb;
  ushort_t* yp = (ushort_t*)(wsb + 3145728);
  float* degp = (float*)(wsb + 28311552);
  float* rdeg = (float*)(wsb + 30408704);
  float* pool = (float*)(wsb + 30539776);

  kA_g<<<dim3(128), dim3(256), 0, stream>>>(aa, wconv, g);
  kB_main<<<dim3(1024), dim3(256), 0, stream>>>(adjs, g, yp, degp);
  kD0_rdeg<<<dim3(64), dim3(256), 0, stream>>>(degp, rdeg);
  kD1_pool<<<dim3(24, 64), dim3(256), 0, stream>>>(yp, rdeg, pool);
  kD2_out<<<dim3(1), dim3(128), 0, stream>>>(pool, wcomb, out);
}

// Round 9
// 107.788 us; speedup vs baseline: 1.7857x; 1.2511x over previous
//
#include <hip/hip_runtime.h>
#include <math.h>

// Problem constants
#define D_DOM 64
#define S_RES 512
#define R_ROWS 2048
#define NAA 20
#define NF 12
#define NB 2
#define NJ 24       // NB*NF
#define NPC 16      // p-chunks per domain (128 rows each)
#define BROWS 8     // rows per stage batch (16 KB f32, 4 p)
#define NBATCH 16   // batches per block
#define BSTR 520    // bf16 row stride (+8 pad: rows land on distinct bank quads)

typedef unsigned short ushort_t;
typedef unsigned int uint_t;
typedef short bf16x8 __attribute__((ext_vector_type(8)));   // 8 bf16 = 4 VGPR
typedef float f32x4 __attribute__((ext_vector_type(4)));

// bf16 helpers (RNE), dependency-free — validated R4-R8
__device__ __forceinline__ ushort_t f2bf(float x) {
  uint_t u = __float_as_uint(x);
  uint_t r = u + 0x7FFFu + ((u >> 16) & 1u);
  return (ushort_t)(r >> 16);
}
__device__ __forceinline__ float bflo(uint_t u) { return __uint_as_float(u << 16); }
__device__ __forceinline__ float bfhi(uint_t u) { return __uint_as_float(u & 0xFFFF0000u); }
__device__ __forceinline__ uint_t pk2(float a, float b) {
  return (uint_t)f2bf(a) | ((uint_t)f2bf(b) << 16);
}

// Direct global->LDS DMA, 16 B/lane (dest wave-uniform base).
__device__ __forceinline__ void gload_lds16(const float* g, float* l) {
  __builtin_amdgcn_global_load_lds((const __attribute__((address_space(1))) void*)g,
                                   (__attribute__((address_space(3))) void*)l,
                                   16, 0, 0);
}

// ---------------------------------------------------------------------------
// Kernel A (R7-validated): G[d][j][k] bf16, k<512 -> g0[j,s], k>=512 -> g1[j,s]
// ---------------------------------------------------------------------------
__global__ __launch_bounds__(256) void kA_g(const float* __restrict__ aa,
                                            const float* __restrict__ wconv,
                                            ushort_t* __restrict__ g) {
  __shared__ float ws[NF * NAA * 2];
  const int tid = threadIdx.x;
  for (int i = tid; i < NF * NAA * 2; i += 256) ws[i] = wconv[i];
  __syncthreads();
  const int pos = blockIdx.x * 256 + tid;  // d*512 + s
  float av[NB][NAA];
#pragma unroll
  for (int b = 0; b < NB; ++b)
#pragma unroll
    for (int c = 0; c < NAA; ++c)
      av[b][c] = aa[(size_t)(b * NAA + c) * (D_DOM * S_RES) + pos];
  const int d = pos >> 9;
  const int s = pos & 511;
#pragma unroll
  for (int b = 0; b < NB; ++b)
#pragma unroll
    for (int f = 0; f < NF; ++f) {
      float s0 = 0.f, s1 = 0.f;
#pragma unroll
      for (int c = 0; c < NAA; ++c) {
        const float a = av[b][c];
        s0 = fmaf(a, ws[(f * NAA + c) * 2 + 0], s0);
        s1 = fmaf(a, ws[(f * NAA + c) * 2 + 1], s1);
      }
      const int j = b * NF + f;
      g[((size_t)(d * NJ + j)) * 1024 + s] = f2bf(s0);
      g[((size_t)(d * NJ + j)) * 1024 + 512 + s] = f2bf(s1);
    }
}

// ---------------------------------------------------------------------------
// Kernel B v9: R8 gload_lds skeleton + R7's verified MFMA h-GEMM.
// 1024 blocks x 256 thr (4 waves); block=(d,pc) covers 128 rows (64 p).
// Per batch t (8 rows = 4 p):
//   [vmcnt(0); lgkm+barrier A]           -- STAGE(t) resident; compute(t-1) done
//   STAGE(t+1) -> rows[(t+1)&1]          -- overlaps whole batch
//   cvt(t): rows f32 -> Bs16[t&1] bf16   -- 16 elem/thread
//   Y(t-1): y += h(t-1) x Ae(t-1)        -- lagged: hs[2]/Bs16[2] ping-pong
//   [lgkm+barrier B]                     -- Bs16(t) visible
//   deg(t) from Bs16; h-MFMA(t): 16 x mfma_16x16x32_bf16 -> hs[t&1]
// Wave roles: w=(mt,kh) for MFMA (R7 layout, HW-validated); lane l owns
// s=l*8..+7 for y/deg. vmcnt never drains mid-compute; barriers drain lgkm
// only. NO min-waves launch_bounds (R5 spill lesson); no reg-staging (R7
// lesson). LDS 52.25 KB -> 3 blocks/CU.
// ---------------------------------------------------------------------------
__global__ __launch_bounds__(256) void kB_main(const float* __restrict__ adjs,
                                               const ushort_t* __restrict__ g,
                                               ushort_t* __restrict__ yp,
                                               float* __restrict__ degp) {
  const int tid = threadIdx.x;
  const int w = tid >> 6;   // 0..3
  const int l = tid & 63;
  const int d = blockIdx.x >> 4;
  const int pc = blockIdx.x & 15;

  const int mt = w & 1, kh = w >> 1;
  const int jl = l & 15, kg = l >> 4;
  const int pl = jl & 3;  // B-frag p (cols 4-15 duplicate 0-3, ignored)

  __shared__ float rows[2][BROWS][S_RES];          // 32 KB f32 stage (dbuf)
  __shared__ __align__(16) ushort_t Bs16[2][BROWS][BSTR];  // 16.25 KB bf16 (dbuf)
  __shared__ __align__(16) float hs[2][2][2][16][4];       // [buf][kh][mt][j][p] 4 KB

  const float* ablk = adjs + ((size_t)d * R_ROWS + (size_t)pc * 128) * S_RES;

  // A-frags: this wave's (mt, kh): 16 ksteps x 8 bf16 (64 VGPR, loop-invariant)
  bf16x8 gf[16];
  {
    const int j_a = mt * 16 + jl;
    const bool valid = (j_a < NJ);
    const ushort_t* gr =
        g + ((size_t)(d * NJ + (valid ? j_a : 0))) * 1024 + kh * 512 + kg * 8;
    const bf16x8 z = {};
#pragma unroll
    for (int ks = 0; ks < 16; ++ks) {
      bf16x8 v = *(const bf16x8*)(gr + ks * 32);
      gf[ks] = valid ? v : z;
    }
  }

  float yv[6][8];  // wave's 6 j x lane's 8 s
#pragma unroll
  for (int jj = 0; jj < 6; ++jj)
#pragma unroll
    for (int e = 0; e < 8; ++e) yv[jj][e] = 0.f;
  float dgv[8];  // deg partial (rows 2w,2w+1 over all batches), lane's 8 s
#pragma unroll
  for (int e = 0; e < 8; ++e) dgv[e] = 0.f;

#define STAGE(T)                                                               \
  {                                                                            \
    _Pragma("unroll")                                                          \
    for (int q = 0; q < 4; ++q) {                                              \
      const int u_ = w * 4 + q;                                                \
      const int row_ = u_ >> 1;                                                \
      const int half_ = u_ & 1;                                                \
      gload_lds16(ablk + ((size_t)((T)*BROWS + row_)) * S_RES + half_ * 256 +  \
                      l * 4,                                                   \
                  &rows[(T) & 1][row_][half_ * 256]);                          \
    }                                                                          \
  }

#define Y_PHASE(TT)                                                            \
  {                                                                            \
    const int buf_ = (TT) & 1;                                                 \
    float ae[4][8];                                                            \
    _Pragma("unroll") for (int p = 0; p < 4; ++p) {                            \
      const uint4 v = *(const uint4*)&Bs16[buf_][p * 2][l * 8];                \
      ae[p][0] = bflo(v.x); ae[p][1] = bfhi(v.x);                              \
      ae[p][2] = bflo(v.y); ae[p][3] = bfhi(v.y);                              \
      ae[p][4] = bflo(v.z); ae[p][5] = bfhi(v.z);                              \
      ae[p][6] = bflo(v.w); ae[p][7] = bfhi(v.w);                              \
    }                                                                          \
    _Pragma("unroll") for (int jj = 0; jj < 6; ++jj) {                         \
      const int j_ = w * 6 + jj;                                               \
      const int jt_ = j_ >> 4, jlo_ = j_ & 15;                                 \
      const f32x4 ha = *(const f32x4*)&hs[buf_][0][jt_][jlo_][0];              \
      const f32x4 hb = *(const f32x4*)&hs[buf_][1][jt_][jlo_][0];              \
      const f32x4 h4 = ha + hb;                                                \
      _Pragma("unroll") for (int p = 0; p < 4; ++p) {                          \
        const float hv = h4[p];                                                \
        _Pragma("unroll") for (int e = 0; e < 8; ++e)                          \
            yv[jj][e] = fmaf(hv, ae[p][e], yv[jj][e]);                         \
      }                                                                        \
    }                                                                          \
  }

  STAGE(0);

  for (int t = 0; t < NBATCH; ++t) {
    asm volatile("s_waitcnt vmcnt(0)" ::: "memory");  // STAGE(t) resident
    asm volatile("s_waitcnt lgkmcnt(0)\n\ts_barrier" ::: "memory");  // A
    if (t + 1 < NBATCH) STAGE(t + 1);

    // cvt(t): rows[t&1] f32 -> Bs16[t&1] bf16. 16 elems/thread.
    {
      const int r_ = tid >> 5;
      const int c0 = (tid & 31) * 16;
      const float4 a = *(const float4*)&rows[t & 1][r_][c0];
      const float4 b = *(const float4*)&rows[t & 1][r_][c0 + 4];
      const float4 c = *(const float4*)&rows[t & 1][r_][c0 + 8];
      const float4 e = *(const float4*)&rows[t & 1][r_][c0 + 12];
      uint4 o0, o1;
      o0.x = pk2(a.x, a.y); o0.y = pk2(a.z, a.w);
      o0.z = pk2(b.x, b.y); o0.w = pk2(b.z, b.w);
      o1.x = pk2(c.x, c.y); o1.y = pk2(c.z, c.w);
      o1.z = pk2(e.x, e.y); o1.w = pk2(e.z, e.w);
      *(uint4*)&Bs16[t & 1][r_][c0] = o0;
      *(uint4*)&Bs16[t & 1][r_][c0 + 8] = o1;
    }

    if (t) Y_PHASE(t - 1);  // lagged y: hs/Bs16 buffers (t-1)&1 are stable

    asm volatile("s_waitcnt lgkmcnt(0)\n\ts_barrier" ::: "memory");  // B

    // deg(t): wave w sums bf16 rows 2w, 2w+1 into dgv (lane's 8 s)
#pragma unroll
    for (int rr = 0; rr < 2; ++rr) {
      const uint4 v = *(const uint4*)&Bs16[t & 1][2 * w + rr][l * 8];
      dgv[0] += bflo(v.x); dgv[1] += bfhi(v.x);
      dgv[2] += bflo(v.y); dgv[3] += bfhi(v.y);
      dgv[4] += bflo(v.z); dgv[5] += bfhi(v.z);
      dgv[6] += bflo(v.w); dgv[7] += bfhi(v.w);
    }

    // h-MFMA(t): 16 x 16x16x32, K = kh*512..+512 (R7-validated layout)
    {
      f32x4 acc = {0.f, 0.f, 0.f, 0.f};
#pragma unroll
      for (int ks = 0; ks < 16; ++ks) {
        const bf16x8 bfr =
            *(const bf16x8*)&Bs16[t & 1][pl * 2 + kh][ks * 32 + kg * 8];
        acc = __builtin_amdgcn_mfma_f32_16x16x32_bf16(gf[ks], bfr, acc, 0, 0, 0);
      }
      if (jl < 4) {
#pragma unroll
        for (int i = 0; i < 4; ++i) hs[t & 1][kh][mt][kg * 4 + i][jl] = acc[i];
      }
    }
  }

  asm volatile("s_waitcnt lgkmcnt(0)\n\ts_barrier" ::: "memory");
  Y_PHASE(NBATCH - 1);

  // y partials -> bf16 yp; deg partials -> degp[d][pc][w][512] f32
  ushort_t* ypb = yp + (size_t)(pc * D_DOM + d) * NJ * S_RES;
#pragma unroll
  for (int jj = 0; jj < 6; ++jj) {
    const int j = w * 6 + jj;
    uint4 o;
    o.x = pk2(yv[jj][0], yv[jj][1]);
    o.y = pk2(yv[jj][2], yv[jj][3]);
    o.z = pk2(yv[jj][4], yv[jj][5]);
    o.w = pk2(yv[jj][6], yv[jj][7]);
    *(uint4*)(ypb + (size_t)j * S_RES + l * 8) = o;
  }
  {
    float* dp = degp + (((size_t)(d * NPC + pc)) * 4 + w) * S_RES + l * 8;
    *(float4*)dp = make_float4(dgv[0], dgv[1], dgv[2], dgv[3]);
    *(float4*)(dp + 4) = make_float4(dgv[4], dgv[5], dgv[6], dgv[7]);
  }
}

// ---------------------------------------------------------------------------
// Kernel D0: rdeg[d][s] = 1 / sum over 64 partials (16 pc x 4 w).
// ---------------------------------------------------------------------------
__global__ __launch_bounds__(256) void kD0_rdeg(const float* __restrict__ degp,
                                                float* __restrict__ rdeg) {
  const int d = blockIdx.x;
  const int tid = threadIdx.x;
  float dg0 = 0.f, dg1 = 0.f;
  const float* base = degp + (size_t)d * NPC * 4 * S_RES;
#pragma unroll 8
  for (int k = 0; k < NPC * 4; ++k) {
    const float2 dv = *(const float2*)(base + (size_t)k * S_RES + 2 * tid);
    dg0 += dv.x;
    dg1 += dv.y;
  }
  *(float2*)(rdeg + (size_t)d * S_RES + 2 * tid) = make_float2(1.f / dg0, 1.f / dg1);
}

// ---------------------------------------------------------------------------
// Kernel D1: pooled[d][j] = max_s (sum_pc yp) * rdeg.  grid (24, 64).
// ---------------------------------------------------------------------------
__global__ __launch_bounds__(256) void kD1_pool(const ushort_t* __restrict__ yp,
                                                const float* __restrict__ rdeg,
                                                float* __restrict__ pool) {
  const int j = blockIdx.x;
  const int d = blockIdx.y;
  const int tid = threadIdx.x;
  __shared__ float wmax[4];

  float v0 = 0.f, v1 = 0.f;
#pragma unroll
  for (int pc = 0; pc < NPC; ++pc) {
    const ushort2 yv =
        *(const ushort2*)(yp + ((size_t)(pc * D_DOM + d) * NJ + j) * S_RES + 2 * tid);
    v0 += bflo((uint_t)yv.x << 16) * 0.f + __uint_as_float((uint_t)yv.x << 16);
    v1 += __uint_as_float((uint_t)yv.y << 16);
  }
  const float2 rv = *(const float2*)(rdeg + (size_t)d * S_RES + 2 * tid);
  float m = fmaxf(v0 * rv.x, v1 * rv.y);
#pragma unroll
  for (int mask = 32; mask; mask >>= 1) m = fmaxf(m, __shfl_xor(m, mask));
  if ((tid & 63) == 0) wmax[tid >> 6] = m;
  __syncthreads();
  if (tid == 0)
    pool[d * NJ + j] = fmaxf(fmaxf(wmax[0], wmax[1]), fmaxf(wmax[2], wmax[3]));
}

// ---------------------------------------------------------------------------
// Kernel D2: out = sigmoid(pool @ w_combine). 1 block.
// ---------------------------------------------------------------------------
__global__ __launch_bounds__(128) void kD2_out(const float* __restrict__ pool,
                                               const float* __restrict__ wcomb,
                                               float* __restrict__ out) {
  const int t = threadIdx.x;
  if (t < D_DOM * NB) {
    const int d = t >> 1, b = t & 1;
    float sc = 0.f;
#pragma unroll
    for (int f = 0; f < NF; ++f) sc = fmaf(pool[d * NJ + b * NF + f], wcomb[f], sc);
    out[t] = 1.0f / (1.0f + expf(-sc));
  }
}

// ---------------------------------------------------------------------------
extern "C" void kernel_launch(void* const* d_in, const int* in_sizes, int n_in,
                              void* d_out, int out_size, void* d_ws, size_t ws_size,
                              hipStream_t stream) {
  const float* aa = (const float*)d_in[0];
  const float* adjs = (const float*)d_in[1];
  const float* wconv = (const float*)d_in[2];
  const float* wcomb = (const float*)d_in[3];
  float* out = (float*)d_out;
  char* wsb = (char*)d_ws;

  // ws layout (bytes):
  //   g    bf16 [64][24][1024]   @ 0          = 3,145,728
  //   yp   bf16 [16*64*24*512]   @ 3,145,728  = 25,165,824
  //   degp f32  [64*16*4*512]    @ 28,311,552 = 8,388,608
  //   rdeg f32  [64*512]         @ 36,700,160 = 131,072
  //   pool f32  [64*24]          @ 36,831,232 = 6,144     (total ~36.8 MB)
  ushort_t* g = (ushort_t*)wsb;
  ushort_t* yp = (ushort_t*)(wsb + 3145728);
  float* degp = (float*)(wsb + 28311552);
  float* rdeg = (float*)(wsb + 36700160);
  float* pool = (float*)(wsb + 36831232);

  kA_g<<<dim3(128), dim3(256), 0, stream>>>(aa, wconv, g);
  kB_main<<<dim3(1024), dim3(256), 0, stream>>>(adjs, g, yp, degp);
  kD0_rdeg<<<dim3(64), dim3(256), 0, stream>>>(degp, rdeg);
  kD1_pool<<<dim3(24, 64), dim3(256), 0, stream>>>(yp, rdeg, pool);
  kD2_out<<<dim3(1), dim3(128), 0, stream>>>(pool, wcomb, out);
}

// Round 10
// 94.698 us; speedup vs baseline: 2.0326x; 1.1382x over previous
//
#include <hip/hip_runtime.h>
#include <math.h>

// Problem constants
#define D_DOM 64
#define S_RES 512
#define R_ROWS 2048
#define NAA 20
#define NF 12
#define NB 2
#define NJ 24       // NB*NF
#define NPC 8       // p-chunks per domain (256 rows each)
#define BROWS 8     // rows per stage batch (16 KB f32, 4 p)
#define NBATCH 32   // batches per block (256 rows)
#define BSTR 520    // bf16 row stride (+8 pad)

typedef unsigned short ushort_t;
typedef unsigned int uint_t;
typedef short bf16x8 __attribute__((ext_vector_type(8)));   // 8 bf16 = 4 VGPR
typedef float f32x4 __attribute__((ext_vector_type(4)));

// bf16 helpers (RNE), dependency-free — validated R4-R9
__device__ __forceinline__ ushort_t f2bf(float x) {
  uint_t u = __float_as_uint(x);
  uint_t r = u + 0x7FFFu + ((u >> 16) & 1u);
  return (ushort_t)(r >> 16);
}
__device__ __forceinline__ float bflo(uint_t u) { return __uint_as_float(u << 16); }
__device__ __forceinline__ float bfhi(uint_t u) { return __uint_as_float(u & 0xFFFF0000u); }
__device__ __forceinline__ uint_t pk2(float a, float b) {
  return (uint_t)f2bf(a) | ((uint_t)f2bf(b) << 16);
}

// Direct global->LDS DMA, 16 B/lane (dest wave-uniform base).
__device__ __forceinline__ void gload_lds16(const float* g, float* l) {
  __builtin_amdgcn_global_load_lds((const __attribute__((address_space(1))) void*)g,
                                   (__attribute__((address_space(3))) void*)l,
                                   16, 0, 0);
}

// ---------------------------------------------------------------------------
// Kernel A: G[d][j][k] bf16 (k<512: g0[j,s]; k>=512: g1[j,s]).
// grid (128, 2): y = b. Split over b halves per-thread work (R10).
// ---------------------------------------------------------------------------
__global__ __launch_bounds__(256) void kA_g(const float* __restrict__ aa,
                                            const float* __restrict__ wconv,
                                            ushort_t* __restrict__ g) {
  __shared__ float ws[NF * NAA * 2];
  const int tid = threadIdx.x;
  for (int i = tid; i < NF * NAA * 2; i += 256) ws[i] = wconv[i];
  __syncthreads();
  const int pos = blockIdx.x * 256 + tid;  // d*512 + s
  const int b = blockIdx.y;
  float av[NAA];
#pragma unroll
  for (int c = 0; c < NAA; ++c)
    av[c] = aa[(size_t)(b * NAA + c) * (D_DOM * S_RES) + pos];
  const int d = pos >> 9;
  const int s = pos & 511;
#pragma unroll
  for (int f = 0; f < NF; ++f) {
    float s0 = 0.f, s1 = 0.f;
#pragma unroll
    for (int c = 0; c < NAA; ++c) {
      const float a = av[c];
      s0 = fmaf(a, ws[(f * NAA + c) * 2 + 0], s0);
      s1 = fmaf(a, ws[(f * NAA + c) * 2 + 1], s1);
    }
    const int j = b * NF + f;
    g[((size_t)(d * NJ + j)) * 1024 + s] = f2bf(s0);
    g[((size_t)(d * NJ + j)) * 1024 + 512 + s] = f2bf(s1);
  }
}

// ---------------------------------------------------------------------------
// Kernel B (R9 core, NPC=8): 512 blocks x 256 thr (4 waves); block=(d,pc)
// covers 256 rows (128 p) in 32 batches of 8 rows.
// Per batch t: [vmcnt(0); lgkm+barrier A] STAGE(t+1); cvt(t); Y(t-1) lagged;
// [lgkm+barrier B]; deg(t); h-MFMA(t) 16x mfma_16x16x32_bf16.
// 2 blocks/CU: VALU/batch/SIMD ~1680cy < HBM/batch ~3120cy -> HBM-shadowed.
// NO min-waves launch_bounds (R5); no reg-staging (R7). LDS 52.25 KB.
// ---------------------------------------------------------------------------
__global__ __launch_bounds__(256) void kB_main(const float* __restrict__ adjs,
                                               const ushort_t* __restrict__ g,
                                               ushort_t* __restrict__ yp,
                                               float* __restrict__ degp) {
  const int tid = threadIdx.x;
  const int w = tid >> 6;   // 0..3
  const int l = tid & 63;
  const int d = blockIdx.x >> 3;
  const int pc = blockIdx.x & 7;

  const int mt = w & 1, kh = w >> 1;
  const int jl = l & 15, kg = l >> 4;
  const int pl = jl & 3;  // B-frag p (cols 4-15 duplicate 0-3, ignored)

  __shared__ float rows[2][BROWS][S_RES];                  // 32 KB f32 (dbuf)
  __shared__ __align__(16) ushort_t Bs16[2][BROWS][BSTR];  // 16.25 KB (dbuf)
  __shared__ __align__(16) float hs[2][2][2][16][4];       // 4 KB

  const float* ablk = adjs + ((size_t)d * R_ROWS + (size_t)pc * 256) * S_RES;

  // A-frags: wave's (mt, kh): 16 ksteps x 8 bf16 (loop-invariant, 64 VGPR)
  bf16x8 gf[16];
  {
    const int j_a = mt * 16 + jl;
    const bool valid = (j_a < NJ);
    const ushort_t* gr =
        g + ((size_t)(d * NJ + (valid ? j_a : 0))) * 1024 + kh * 512 + kg * 8;
    const bf16x8 z = {};
#pragma unroll
    for (int ks = 0; ks < 16; ++ks) {
      bf16x8 v = *(const bf16x8*)(gr + ks * 32);
      gf[ks] = valid ? v : z;
    }
  }

  float yv[6][8];
#pragma unroll
  for (int jj = 0; jj < 6; ++jj)
#pragma unroll
    for (int e = 0; e < 8; ++e) yv[jj][e] = 0.f;
  float dgv[8];
#pragma unroll
  for (int e = 0; e < 8; ++e) dgv[e] = 0.f;

#define STAGE(T)                                                               \
  {                                                                            \
    _Pragma("unroll")                                                          \
    for (int q = 0; q < 4; ++q) {                                              \
      const int u_ = w * 4 + q;                                                \
      const int row_ = u_ >> 1;                                                \
      const int half_ = u_ & 1;                                                \
      gload_lds16(ablk + ((size_t)((T)*BROWS + row_)) * S_RES + half_ * 256 +  \
                      l * 4,                                                   \
                  &rows[(T) & 1][row_][half_ * 256]);                          \
    }                                                                          \
  }

#define Y_PHASE(TT)                                                            \
  {                                                                            \
    const int buf_ = (TT) & 1;                                                 \
    float ae[4][8];                                                            \
    _Pragma("unroll") for (int p = 0; p < 4; ++p) {                            \
      const uint4 v = *(const uint4*)&Bs16[buf_][p * 2][l * 8];                \
      ae[p][0] = bflo(v.x); ae[p][1] = bfhi(v.x);                              \
      ae[p][2] = bflo(v.y); ae[p][3] = bfhi(v.y);                              \
      ae[p][4] = bflo(v.z); ae[p][5] = bfhi(v.z);                              \
      ae[p][6] = bflo(v.w); ae[p][7] = bfhi(v.w);                              \
    }                                                                          \
    _Pragma("unroll") for (int jj = 0; jj < 6; ++jj) {                         \
      const int j_ = w * 6 + jj;                                               \
      const int jt_ = j_ >> 4, jlo_ = j_ & 15;                                 \
      const f32x4 ha = *(const f32x4*)&hs[buf_][0][jt_][jlo_][0];              \
      const f32x4 hb = *(const f32x4*)&hs[buf_][1][jt_][jlo_][0];              \
      const f32x4 h4 = ha + hb;                                                \
      _Pragma("unroll") for (int p = 0; p < 4; ++p) {                          \
        const float hv = h4[p];                                                \
        _Pragma("unroll") for (int e = 0; e < 8; ++e)                          \
            yv[jj][e] = fmaf(hv, ae[p][e], yv[jj][e]);                         \
      }                                                                        \
    }                                                                          \
  }

  STAGE(0);

  for (int t = 0; t < NBATCH; ++t) {
    asm volatile("s_waitcnt vmcnt(0)" ::: "memory");  // STAGE(t) resident
    asm volatile("s_waitcnt lgkmcnt(0)\n\ts_barrier" ::: "memory");  // A
    if (t + 1 < NBATCH) STAGE(t + 1);

    // cvt(t): rows[t&1] f32 -> Bs16[t&1] bf16. 16 elems/thread.
    {
      const int r_ = tid >> 5;
      const int c0 = (tid & 31) * 16;
      const float4 a = *(const float4*)&rows[t & 1][r_][c0];
      const float4 b = *(const float4*)&rows[t & 1][r_][c0 + 4];
      const float4 c = *(const float4*)&rows[t & 1][r_][c0 + 8];
      const float4 e = *(const float4*)&rows[t & 1][r_][c0 + 12];
      uint4 o0, o1;
      o0.x = pk2(a.x, a.y); o0.y = pk2(a.z, a.w);
      o0.z = pk2(b.x, b.y); o0.w = pk2(b.z, b.w);
      o1.x = pk2(c.x, c.y); o1.y = pk2(c.z, c.w);
      o1.z = pk2(e.x, e.y); o1.w = pk2(e.z, e.w);
      *(uint4*)&Bs16[t & 1][r_][c0] = o0;
      *(uint4*)&Bs16[t & 1][r_][c0 + 8] = o1;
    }

    if (t) Y_PHASE(t - 1);  // lagged y: (t-1)&1 buffers stable

    asm volatile("s_waitcnt lgkmcnt(0)\n\ts_barrier" ::: "memory");  // B

    // deg(t): wave w sums bf16 rows 2w, 2w+1 (lane's 8 s)
#pragma unroll
    for (int rr = 0; rr < 2; ++rr) {
      const uint4 v = *(const uint4*)&Bs16[t & 1][2 * w + rr][l * 8];
      dgv[0] += bflo(v.x); dgv[1] += bfhi(v.x);
      dgv[2] += bflo(v.y); dgv[3] += bfhi(v.y);
      dgv[4] += bflo(v.z); dgv[5] += bfhi(v.z);
      dgv[6] += bflo(v.w); dgv[7] += bfhi(v.w);
    }

    // h-MFMA(t): 16 x 16x16x32 (R7/R9-validated layout)
    {
      f32x4 acc = {0.f, 0.f, 0.f, 0.f};
#pragma unroll
      for (int ks = 0; ks < 16; ++ks) {
        const bf16x8 bfr =
            *(const bf16x8*)&Bs16[t & 1][pl * 2 + kh][ks * 32 + kg * 8];
        acc = __builtin_amdgcn_mfma_f32_16x16x32_bf16(gf[ks], bfr, acc, 0, 0, 0);
      }
      if (jl < 4) {
#pragma unroll
        for (int i = 0; i < 4; ++i) hs[t & 1][kh][mt][kg * 4 + i][jl] = acc[i];
      }
    }
  }

  asm volatile("s_waitcnt lgkmcnt(0)\n\ts_barrier" ::: "memory");
  Y_PHASE(NBATCH - 1);

  // y partials -> bf16 yp; deg partials -> degp f32
  ushort_t* ypb = yp + (size_t)(pc * D_DOM + d) * NJ * S_RES;
#pragma unroll
  for (int jj = 0; jj < 6; ++jj) {
    const int j = w * 6 + jj;
    uint4 o;
    o.x = pk2(yv[jj][0], yv[jj][1]);
    o.y = pk2(yv[jj][2], yv[jj][3]);
    o.z = pk2(yv[jj][4], yv[jj][5]);
    o.w = pk2(yv[jj][6], yv[jj][7]);
    *(uint4*)(ypb + (size_t)j * S_RES + l * 8) = o;
  }
  {
    float* dp = degp + (((size_t)(d * NPC + pc)) * 4 + w) * S_RES + l * 8;
    *(float4*)dp = make_float4(dgv[0], dgv[1], dgv[2], dgv[3]);
    *(float4*)(dp + 4) = make_float4(dgv[4], dgv[5], dgv[6], dgv[7]);
  }
}

// ---------------------------------------------------------------------------
// Kernel D0: rdeg[d][s] = 1 / sum over 32 partials (8 pc x 4 w).
// ---------------------------------------------------------------------------
__global__ __launch_bounds__(256) void kD0_rdeg(const float* __restrict__ degp,
                                                float* __restrict__ rdeg) {
  const int d = blockIdx.x;
  const int tid = threadIdx.x;
  float dg0 = 0.f, dg1 = 0.f;
  const float* base = degp + (size_t)d * NPC * 4 * S_RES;
#pragma unroll 8
  for (int k = 0; k < NPC * 4; ++k) {
    const float2 dv = *(const float2*)(base + (size_t)k * S_RES + 2 * tid);
    dg0 += dv.x;
    dg1 += dv.y;
  }
  *(float2*)(rdeg + (size_t)d * S_RES + 2 * tid) = make_float2(1.f / dg0, 1.f / dg1);
}

// ---------------------------------------------------------------------------
// Kernel D1: pooled[d][j] = max_s (sum_pc yp) * rdeg.  grid (24, 64).
// ---------------------------------------------------------------------------
__global__ __launch_bounds__(256) void kD1_pool(const ushort_t* __restrict__ yp,
                                                const float* __restrict__ rdeg,
                                                float* __restrict__ pool) {
  const int j = blockIdx.x;
  const int d = blockIdx.y;
  const int tid = threadIdx.x;
  __shared__ float wmax[4];

  float v0 = 0.f, v1 = 0.f;
#pragma unroll
  for (int pc = 0; pc < NPC; ++pc) {
    const ushort2 yv =
        *(const ushort2*)(yp + ((size_t)(pc * D_DOM + d) * NJ + j) * S_RES + 2 * tid);
    v0 += __uint_as_float((uint_t)yv.x << 16);
    v1 += __uint_as_float((uint_t)yv.y << 16);
  }
  const float2 rv = *(const float2*)(rdeg + (size_t)d * S_RES + 2 * tid);
  float m = fmaxf(v0 * rv.x, v1 * rv.y);
#pragma unroll
  for (int mask = 32; mask; mask >>= 1) m = fmaxf(m, __shfl_xor(m, mask));
  if ((tid & 63) == 0) wmax[tid >> 6] = m;
  __syncthreads();
  if (tid == 0)
    pool[d * NJ + j] = fmaxf(fmaxf(wmax[0], wmax[1]), fmaxf(wmax[2], wmax[3]));
}

// ---------------------------------------------------------------------------
// Kernel D2: out = sigmoid(pool @ w_combine). 1 block.
// ---------------------------------------------------------------------------
__global__ __launch_bounds__(128) void kD2_out(const float* __restrict__ pool,
                                               const float* __restrict__ wcomb,
                                               float* __restrict__ out) {
  const int t = threadIdx.x;
  if (t < D_DOM * NB) {
    const int d = t >> 1, b = t & 1;
    float sc = 0.f;
#pragma unroll
    for (int f = 0; f < NF; ++f) sc = fmaf(pool[d * NJ + b * NF + f], wcomb[f], sc);
    out[t] = 1.0f / (1.0f + expf(-sc));
  }
}

// ---------------------------------------------------------------------------
extern "C" void kernel_launch(void* const* d_in, const int* in_sizes, int n_in,
                              void* d_out, int out_size, void* d_ws, size_t ws_size,
                              hipStream_t stream) {
  const float* aa = (const float*)d_in[0];
  const float* adjs = (const float*)d_in[1];
  const float* wconv = (const float*)d_in[2];
  const float* wcomb = (const float*)d_in[3];
  float* out = (float*)d_out;
  char* wsb = (char*)d_ws;

  // ws layout (bytes):
  //   g    bf16 [64][24][1024] @ 0          = 3,145,728
  //   yp   bf16 [8*64*24*512]  @ 3,145,728  = 12,582,912
  //   degp f32  [64*8*4*512]   @ 15,728,640 = 4,194,304
  //   rdeg f32  [64*512]       @ 19,922,944 = 131,072
  //   pool f32  [64*24]        @ 20,054,016 = 6,144     (total ~20.1 MB)
  ushort_t* g = (ushort_t*)wsb;
  ushort_t* yp = (ushort_t*)(wsb + 3145728);
  float* degp = (float*)(wsb + 15728640);
  float* rdeg = (float*)(wsb + 19922944);
  float* pool = (float*)(wsb + 20054016);

  kA_g<<<dim3(128, 2), dim3(256), 0, stream>>>(aa, wconv, g);
  kB_main<<<dim3(512), dim3(256), 0, stream>>>(adjs, g, yp, degp);
  kD0_rdeg<<<dim3(64), dim3(256), 0, stream>>>(degp, rdeg);
  kD1_pool<<<dim3(24, 64), dim3(256), 0, stream>>>(yp, rdeg, pool);
  kD2_out<<<dim3(1), dim3(128), 0, stream>>>(pool, wcomb, out);
}